// Round 7
// baseline (811.171 us; speedup 1.0000x reference)
//
#include <hip/hip_runtime.h>
#include <hip/hip_bf16.h>

typedef __bf16 bf16_t;
typedef unsigned short u16;
typedef short short8 __attribute__((ext_vector_type(8)));
typedef float f32x4 __attribute__((ext_vector_type(4)));

#define BSHIFT 10           // 1024 dst-rows per bucket
#define TILE 8192
#define LSTRIDE 72          // LDS mean-row stride in u16 (bank-conflict-safe)

__device__ inline short f2bs(float v) {
    bf16_t h = (bf16_t)v;
    return __builtin_bit_cast(short, h);
}
__device__ inline float uif(unsigned u) { return __builtin_bit_cast(float, u); }

// ---------------- prep: feature cvt (f32->bf16) + weight transpose ----------------
// weight mats in wh (transposed, [n*64+k]): 0..5 Wn[l*3+e]; 6,7 WrB[l]=Wr[l,0];
// 8,9 WrA[l]=Wr[l,1]+Wr[l,2] (f32 pre-sum); 10 W_out.
__global__ __launch_bounds__(256) void prep_kernel(
    const float* __restrict__ xA, const float* __restrict__ xB,
    const float* __restrict__ Wn, const float* __restrict__ Wr,
    const float* __restrict__ Wout,
    u16* __restrict__ plane0, u16* __restrict__ wh, int NA, int NB) {
    int nA4 = NA * 16, nB4 = NB * 16;
    int bA = (nA4 + 255) / 256, bB = (nB4 + 255) / 256;
    int bi = blockIdx.x;
    if (bi < bA + bB) {
        const float* in = (bi < bA) ? xA : xB;
        u16* out = (bi < bA) ? plane0 : plane0 + (size_t)NA * 64;
        int i = (bi < bA ? bi : bi - bA) * 256 + threadIdx.x;
        int n4 = (bi < bA) ? nA4 : nB4;
        if (i >= n4) return;
        float4 v = ((const float4*)in)[i];
        u16 o[4];
        o[0] = (u16)f2bs(v.x); o[1] = (u16)f2bs(v.y);
        o[2] = (u16)f2bs(v.z); o[3] = (u16)f2bs(v.w);
        *(uint2*)(out + (size_t)i * 4) = *(uint2*)o;
        return;
    }
    int mat = bi - bA - bB;      // 0..10
    u16* dstp = wh + (size_t)mat * 4096;
    for (int i = threadIdx.x; i < 4096; i += 256) {
        int k = i >> 6, n = i & 63;
        float v;
        if (mat < 6) v = Wn[(size_t)mat * 4096 + i];
        else if (mat < 8) v = Wr[(size_t)((mat - 6) * 3 + 0) * 4096 + i];
        else if (mat < 10) v = Wr[(size_t)((mat - 8) * 3 + 1) * 4096 + i]
                             + Wr[(size_t)((mat - 8) * 3 + 2) * 4096 + i];
        else v = Wout[i];
        dstp[n * 64 + k] = (u16)f2bs(v);
    }
}

// ---------------- CSR build: bucketed multisplit ----------------
__global__ __launch_bounds__(256) void bucket_count(const int* __restrict__ d0,
                                                    const int* __restrict__ d1,
                                                    const int* __restrict__ d2,
                                                    int* __restrict__ ghist,
                                                    int NB, int NA, int E, int total, int K) {
    __shared__ int h[1024];
    int tid = threadIdx.x;
    for (int i = tid; i < 1024; i += 256) h[i] = 0;
    __syncthreads();
    for (int i = blockIdx.x * 256 + tid; i < total; i += gridDim.x * 256) {
        int g;
        if (i < E) g = d0[i];
        else if (i < 2 * E) g = NB + d1[i - E];
        else g = NB + NA + d2[i - 2 * E];
        atomicAdd(&h[g >> BSHIFT], 1);
    }
    __syncthreads();
    for (int i = tid; i < K; i += 256)
        if (h[i]) atomicAdd(&ghist[i], h[i]);
}

__global__ __launch_bounds__(256) void bucket_scan(const int* __restrict__ ghist,
                                                   int* __restrict__ bbase,
                                                   int* __restrict__ gcursor,
                                                   int K, int total) {
    __shared__ int ssum[256];
    int tid = threadIdx.x;
    int v[4]; int s = 0;
#pragma unroll
    for (int j = 0; j < 4; j++) {
        int i = tid * 4 + j;
        v[j] = s;
        s += (i < K) ? ghist[i] : 0;
    }
    ssum[tid] = s; __syncthreads();
    for (int off = 1; off < 256; off <<= 1) {
        int t = (tid >= off) ? ssum[tid - off] : 0; __syncthreads();
        ssum[tid] += t; __syncthreads();
    }
    int exc = tid ? ssum[tid - 1] : 0;
#pragma unroll
    for (int j = 0; j < 4; j++) {
        int i = tid * 4 + j;
        if (i < K) { bbase[i] = exc + v[j]; gcursor[i] = exc + v[j]; }
    }
    if (tid == 255) bbase[K] = total;
}

__global__ __launch_bounds__(256) void partition_kernel(
    const int* __restrict__ s0, const int* __restrict__ d0,
    const int* __restrict__ s1, const int* __restrict__ d1,
    const int* __restrict__ s2, const int* __restrict__ d2,
    int* __restrict__ gcursor, int2* __restrict__ pairs,
    int NB, int NA, int E, int total) {
    __shared__ int hist[1024];
    __shared__ int gbase[1024];
    __shared__ int ssum[256];
    __shared__ int2 buf[TILE];
    int tid = threadIdx.x;
    for (int tile = blockIdx.x * TILE; tile < total; tile += gridDim.x * TILE) {
        for (int i = tid; i < 1024; i += 256) hist[i] = 0;
        __syncthreads();
        int cnt = min(TILE, total - tile);
        int myg[32], mysrc[32], myrank[32];
#pragma unroll
        for (int j = 0; j < 32; j++) {
            int idx = tile + j * 256 + tid;
            int g = -1, s = 0;
            if (idx < total) {
                if (idx < E) { s = s0[idx]; g = d0[idx]; }
                else if (idx < 2 * E) { s = s1[idx - E]; g = NB + d1[idx - E]; }
                else { s = s2[idx - 2 * E]; g = NB + NA + d2[idx - 2 * E]; }
            }
            myg[j] = g; mysrc[j] = s;
            if (g >= 0) myrank[j] = atomicAdd(&hist[g >> BSHIFT], 1);
        }
        __syncthreads();
        int l[4]; int base4 = tid * 4; int ts = 0;
#pragma unroll
        for (int j = 0; j < 4; j++) { l[j] = hist[base4 + j]; ts += l[j]; }
        ssum[tid] = ts; __syncthreads();
        for (int off = 1; off < 256; off <<= 1) {
            int t = (tid >= off) ? ssum[tid - off] : 0; __syncthreads();
            ssum[tid] += t; __syncthreads();
        }
        int exc = tid ? ssum[tid - 1] : 0;
#pragma unroll
        for (int j = 0; j < 4; j++) {
            hist[base4 + j] = exc;
            if (l[j]) gbase[base4 + j] = atomicAdd(&gcursor[base4 + j], l[j]);
            exc += l[j];
        }
        __syncthreads();
#pragma unroll
        for (int j = 0; j < 32; j++) {
            if (myg[j] >= 0) {
                int bkt = myg[j] >> BSHIFT;
                buf[hist[bkt] + myrank[j]] = make_int2(mysrc[j], myg[j]);
            }
        }
        __syncthreads();
        for (int i = tid; i < cnt; i += 256) {
            int2 p = buf[i];
            int bkt = p.y >> BSHIFT;
            pairs[gbase[bkt] + (i - hist[bkt])] = p;
        }
        __syncthreads();
    }
}

__global__ __launch_bounds__(256) void bucket_fill(const int2* __restrict__ pairs,
                                                   const int* __restrict__ bbase,
                                                   int* __restrict__ off,
                                                   int* __restrict__ colidx,
                                                   int M, int K) {
    int b = blockIdx.x;
    int gb = b << BSHIFT;
    __shared__ int cnt[1024], cur[1024], ssum[256];
    int tid = threadIdx.x;
    int p0 = bbase[b], p1 = bbase[b + 1];
    for (int i = tid; i < 1024; i += 256) cnt[i] = 0;
    __syncthreads();
    for (int e = p0 + tid; e < p1; e += 256)
        atomicAdd(&cnt[pairs[e].y - gb], 1);
    __syncthreads();
    int l[4], ts = 0;
#pragma unroll
    for (int j = 0; j < 4; j++) { l[j] = cnt[tid * 4 + j]; ts += l[j]; }
    ssum[tid] = ts; __syncthreads();
    for (int o = 1; o < 256; o <<= 1) {
        int t = (tid >= o) ? ssum[tid - o] : 0; __syncthreads();
        ssum[tid] += t; __syncthreads();
    }
    int exc = tid ? ssum[tid - 1] : 0;
#pragma unroll
    for (int j = 0; j < 4; j++) {
        cur[tid * 4 + j] = exc;
        int g = gb + tid * 4 + j;
        if (g < M) off[g] = p0 + exc;
        exc += l[j];
    }
    if (b == K - 1 && tid == 0) off[M] = p1;
    __syncthreads();
    for (int e = p0 + tid; e < p1; e += 256) {
        int2 p = pairs[e];
        int pos = atomicAdd(&cur[p.y - gb], 1);
        colidx[p0 + pos] = p.x;
    }
}

// ---------------- fused layer: gather means (wave-local LDS) + MFMA ----------------
// Per wave: gather means for its 16 output rows into LDS (bf16, stride LSTRIDE),
// no barrier (wave-private region), then 16x64 MFMA tile:
//   out = sum_st mean_st @ Wm_st + x @ Wx + bias.
// Layouts: A[m=lane&15][k=(lane>>4)*8+j], B[k][n=lane&15] (pre-transposed),
// C/D row=(lane>>4)*4+reg, col=lane&15.
template <int NM>
__device__ __forceinline__ void layer_body(
    const u16* __restrict__ tab0, int goff0,
    const u16* __restrict__ tab1, int goff1,
    const u16* __restrict__ x,
    const int* __restrict__ colidx, const int* __restrict__ off,
    const u16* __restrict__ Wm0t, const u16* __restrict__ Wm1t,
    const u16* __restrict__ Wxt,
    const float* __restrict__ bias0, const float* __restrict__ bias1,
    u16* __restrict__ out, int nrows, int blk, u16* lds) {
    const int lane = threadIdx.x & 63;
    const int wave = threadIdx.x >> 6;
    const int row0 = blk * 64 + wave * 16;
    if (row0 >= nrows) return;

    // ---- gather phase (wave-private LDS region) ----
    const int qh = lane >> 4, fl = lane & 15;
    const unsigned fo = (unsigned)(fl << 3);
#pragma unroll
    for (int st = 0; st < NM; st++) {
        const char* tab = (const char*)(st ? tab1 : tab0);
        const int goff = st ? goff1 : goff0;
        u16* lrow = lds + st * (64 * LSTRIDE) + wave * 16 * LSTRIDE;
        for (int rr = 0; rr < 16; rr++) {
            int row = row0 + rr;
            if (row >= nrows) break;
            int gid = goff + row;
            int s0 = off[gid], s1 = off[gid + 1];
            f32x4 a0 = {0.f, 0.f, 0.f, 0.f}, a1 = {0.f, 0.f, 0.f, 0.f};
            int e = s0 + qh;
            for (; e + 4 < s1; e += 8) {
                int c0 = colidx[e], c1 = colidx[e + 4];
                uint2 u0 = *(const uint2*)(tab + (((unsigned)c0 << 7) | fo));
                uint2 u1 = *(const uint2*)(tab + (((unsigned)c1 << 7) | fo));
                a0[0] += uif(u0.x << 16); a0[1] += uif(u0.x & 0xFFFF0000u);
                a0[2] += uif(u0.y << 16); a0[3] += uif(u0.y & 0xFFFF0000u);
                a1[0] += uif(u1.x << 16); a1[1] += uif(u1.x & 0xFFFF0000u);
                a1[2] += uif(u1.y << 16); a1[3] += uif(u1.y & 0xFFFF0000u);
            }
            for (; e < s1; e += 4) {
                int c = colidx[e];
                uint2 u = *(const uint2*)(tab + (((unsigned)c << 7) | fo));
                a0[0] += uif(u.x << 16); a0[1] += uif(u.x & 0xFFFF0000u);
                a0[2] += uif(u.y << 16); a0[3] += uif(u.y & 0xFFFF0000u);
            }
#pragma unroll
            for (int i = 0; i < 4; i++) {
                a0[i] += a1[i];
                a0[i] += __shfl_xor(a0[i], 16);
                a0[i] += __shfl_xor(a0[i], 32);
            }
            if (qh == 0) {
                float inv = 1.0f / fmaxf((float)(s1 - s0), 1.0f);
                u16 o[4];
#pragma unroll
                for (int i = 0; i < 4; i++) o[i] = (u16)f2bs(a0[i] * inv);
                *(uint2*)(lrow + rr * LSTRIDE + fl * 4) = *(uint2*)o;
            }
        }
    }
    // no __syncthreads: each wave reads only its own LDS rows

    // ---- MFMA phase ----
    const int r = lane & 15;
    const int q = lane >> 4;

    short8 wm0f[2][4], wm1f[2][4], wxf[2][4];
#pragma unroll
    for (int ks = 0; ks < 2; ks++) {
#pragma unroll
        for (int t = 0; t < 4; t++) {
            size_t widx = (size_t)(t * 16 + r) * 64 + ks * 32 + q * 8;
            wm0f[ks][t] = *(const short8*)(Wm0t + widx);
            if (NM >= 2) wm1f[ks][t] = *(const short8*)(Wm1t + widx);
            wxf[ks][t] = *(const short8*)(Wxt + widx);
        }
    }

    f32x4 acc[4];
#pragma unroll
    for (int t = 0; t < 4; t++) {
        float bv = bias0[t * 16 + r];
        if (NM >= 2) bv += bias1[t * 16 + r];
        acc[t][0] = bv; acc[t][1] = bv; acc[t][2] = bv; acc[t][3] = bv;
    }

    const int arow = row0 + r;
    const bool avalid = arow < nrows;
    short8 zf;
#pragma unroll
    for (int j = 0; j < 8; j++) zf[j] = 0;

    const u16* lbase = lds + (wave * 16 + r) * LSTRIDE;
#pragma unroll
    for (int ks = 0; ks < 2; ks++) {
        short8 af = avalid ? *(const short8*)(lbase + ks * 32 + q * 8) : zf;
#pragma unroll
        for (int t = 0; t < 4; t++)
            acc[t] = __builtin_amdgcn_mfma_f32_16x16x32_bf16(af, wm0f[ks][t], acc[t], 0, 0, 0);
    }
    if (NM >= 2) {
#pragma unroll
        for (int ks = 0; ks < 2; ks++) {
            short8 af = avalid ? *(const short8*)(lbase + 64 * LSTRIDE + ks * 32 + q * 8) : zf;
#pragma unroll
            for (int t = 0; t < 4; t++)
                acc[t] = __builtin_amdgcn_mfma_f32_16x16x32_bf16(af, wm1f[ks][t], acc[t], 0, 0, 0);
        }
    }
#pragma unroll
    for (int ks = 0; ks < 2; ks++) {
        short8 xf = avalid ? *(const short8*)(x + (size_t)arow * 64 + ks * 32 + q * 8) : zf;
#pragma unroll
        for (int t = 0; t < 4; t++)
            acc[t] = __builtin_amdgcn_mfma_f32_16x16x32_bf16(xf, wxf[ks][t], acc[t], 0, 0, 0);
    }

#pragma unroll
    for (int t = 0; t < 4; t++) {
#pragma unroll
        for (int rr = 0; rr < 4; rr++) {
            int row = row0 + q * 4 + rr;
            if (row < nrows)
                out[(size_t)row * 64 + t * 16 + r] = (u16)f2bs(acc[t][rr]);
        }
    }
}

// one layer: B-phase blocks [0,blocksB), A-phase blocks [blocksB, ...)
__global__ __launch_bounds__(256) void layer_kernel(
    const u16* __restrict__ plane_in, u16* __restrict__ plane_out,
    const int* __restrict__ colidx, const int* __restrict__ off,
    const u16* __restrict__ wh, const float* __restrict__ bvec,
    int l, int NA, int NB, int blocksB) {
    __shared__ u16 lds[2 * 64 * LSTRIDE];
    const u16* xAp = plane_in;
    const u16* xBp = plane_in + (size_t)NA * 64;
    if ((int)blockIdx.x < blocksB) {
        // new_B = mean(A->B)@Wn[l,0] + x_B@Wr[l,0] + b[l,0]
        layer_body<1>(xAp, 0, nullptr, 0, xBp, colidx, off,
                      wh + (size_t)(l * 3 + 0) * 4096, nullptr,
                      wh + (size_t)(6 + l) * 4096,
                      bvec + (size_t)(l * 3 + 0) * 64, nullptr,
                      plane_out + (size_t)NA * 64, NB, blockIdx.x, lds);
    } else {
        // new_A = mean(B->A)@Wn[l,1] + mean(A->A)@Wn[l,2] + x_A@(Wr[l,1]+Wr[l,2]) + b[l,1]+b[l,2]
        layer_body<2>(xBp, NB, xAp, NB + NA, xAp, colidx, off,
                      wh + (size_t)(l * 3 + 1) * 4096, wh + (size_t)(l * 3 + 2) * 4096,
                      wh + (size_t)(8 + l) * 4096,
                      bvec + (size_t)(l * 3 + 1) * 64, bvec + (size_t)(l * 3 + 2) * 64,
                      plane_out, NA, blockIdx.x - blocksB, lds);
    }
}

// ---------------- head: relu(x @ W_out + b_out) -> f32 ----------------
__global__ __launch_bounds__(256) void head_kernel(
    const u16* __restrict__ x, const u16* __restrict__ Wt,
    const float* __restrict__ bias, float* __restrict__ out, int nrows) {
    const int lane = threadIdx.x & 63;
    const int wave = threadIdx.x >> 6;
    const int row0 = blockIdx.x * 64 + wave * 16;
    if (row0 >= nrows) return;
    const int r = lane & 15;
    const int q = lane >> 4;
    short8 wf[2][4];
#pragma unroll
    for (int ks = 0; ks < 2; ks++)
#pragma unroll
        for (int t = 0; t < 4; t++)
            wf[ks][t] = *(const short8*)(Wt + (size_t)(t * 16 + r) * 64 + ks * 32 + q * 8);
    f32x4 acc[4];
#pragma unroll
    for (int t = 0; t < 4; t++) {
        float bv = bias[t * 16 + r];
        acc[t][0] = bv; acc[t][1] = bv; acc[t][2] = bv; acc[t][3] = bv;
    }
    const int arow = row0 + r;
    const bool avalid = arow < nrows;
    short8 zf;
#pragma unroll
    for (int j = 0; j < 8; j++) zf[j] = 0;
#pragma unroll
    for (int ks = 0; ks < 2; ks++) {
        short8 xf = avalid ? *(const short8*)(x + (size_t)arow * 64 + ks * 32 + q * 8) : zf;
#pragma unroll
        for (int t = 0; t < 4; t++)
            acc[t] = __builtin_amdgcn_mfma_f32_16x16x32_bf16(xf, wf[ks][t], acc[t], 0, 0, 0);
    }
#pragma unroll
    for (int t = 0; t < 4; t++)
#pragma unroll
        for (int rr = 0; rr < 4; rr++) {
            int row = row0 + q * 4 + rr;
            if (row < nrows)
                out[(size_t)row * 64 + t * 16 + r] = fmaxf(acc[t][rr], 0.0f);
        }
}

// ---------------- launch ----------------
extern "C" void kernel_launch(void* const* d_in, const int* in_sizes, int n_in,
                              void* d_out, int out_size, void* d_ws, size_t ws_size,
                              hipStream_t stream) {
    const float* xA_in = (const float*)d_in[0];
    const float* xB_in = (const float*)d_in[1];
    const float* Wn = (const float*)d_in[2];
    const float* Wr = (const float*)d_in[3];
    const float* b = (const float*)d_in[4];
    const float* W_out = (const float*)d_in[5];
    const float* b_out = (const float*)d_in[6];
    const int* src0 = (const int*)d_in[7];
    const int* dst0 = (const int*)d_in[8];
    const int* src1 = (const int*)d_in[9];
    const int* dst1 = (const int*)d_in[10];
    const int* src2 = (const int*)d_in[11];
    const int* dst2 = (const int*)d_in[12];

    const int NA = in_sizes[0] / 64;
    const int NB = in_sizes[1] / 64;
    const int E = in_sizes[7];
    const int M = NB + NA + NA;
    const int total = 3 * E;
    const int K = (M + (1 << BSHIFT) - 1) >> BSHIFT;

    // ---- workspace ----
    const size_t PL = (size_t)(NA + NB) * 64;
    u16* plane[2];
    plane[0] = (u16*)d_ws;
    plane[1] = plane[0] + PL;
    u16* wh     = plane[1] + PL;                 // 11*4096
    int* ghist  = (int*)(wh + 11 * 4096);
    int* bbase  = ghist + 1024;
    int* gcursor= bbase + 1025;
    int* off    = gcursor + 1024;
    int* colidx = off + (M + 1);
    int2* pairs = (int2*)(colidx + total);

    // ---- prep (cvt + weights) ----
    int bA = (NA * 16 + 255) / 256, bB = (NB * 16 + 255) / 256;
    prep_kernel<<<bA + bB + 11, 256, 0, stream>>>(xA_in, xB_in, Wn, Wr, W_out,
                                                  plane[0], wh, NA, NB);

    // ---- CSR build ----
    hipMemsetAsync(ghist, 0, 1024 * 4, stream);
    bucket_count<<<512, 256, 0, stream>>>(dst0, dst1, dst2, ghist, NB, NA, E, total, K);
    bucket_scan<<<1, 256, 0, stream>>>(ghist, bbase, gcursor, K, total);
    int ntiles = (total + TILE - 1) / TILE;
    partition_kernel<<<ntiles, 256, 0, stream>>>(src0, dst0, src1, dst1, src2, dst2,
                                                 gcursor, pairs, NB, NA, E, total);
    bucket_fill<<<K, 256, 0, stream>>>(pairs, bbase, off, colidx, M, K);

    // ---- layers (fused gather + MFMA) ----
    const int blocksB = (NB + 63) / 64;
    const int blocksA = (NA + 63) / 64;
    int p = 0;
    for (int l = 0; l < 2; l++) {
        layer_kernel<<<blocksB + blocksA, 256, 0, stream>>>(
            plane[p], plane[1 - p], colidx, off, wh, b, l, NA, NB, blocksB);
        p = 1 - p;
    }

    // ---- head ----
    head_kernel<<<(NA + NB + 63) / 64, 256, 0, stream>>>(
        plane[p], wh + (size_t)10 * 4096, b_out, (float*)d_out, NA + NB);
}

// Round 8
// 560.741 us; speedup vs baseline: 1.4466x; 1.4466x over previous
//
#include <hip/hip_runtime.h>
#include <hip/hip_bf16.h>

typedef __bf16 bf16_t;
typedef unsigned short u16;
typedef short short8 __attribute__((ext_vector_type(8)));
typedef float f32x4 __attribute__((ext_vector_type(4)));

#define BSHIFT 10           // 1024 dst-rows per bucket
#define TILE 8192

__device__ inline short f2bs(float v) {
    bf16_t h = (bf16_t)v;
    return __builtin_bit_cast(short, h);
}
__device__ inline float uif(unsigned u) { return __builtin_bit_cast(float, u); }

// ---------------- prep (cvt + weights) + bucket_count, one launch ----------------
// wh mats (transposed [n*64+k]): 0..5 Wn[l*3+e]; 6,7 WrB[l]=Wr[l,0];
// 8,9 WrA[l]=Wr[l,1]+Wr[l,2] (f32 pre-sum); 10 W_out.
__global__ __launch_bounds__(256) void prep_count(
    const float* __restrict__ xA, const float* __restrict__ xB,
    const float* __restrict__ Wn, const float* __restrict__ Wr,
    const float* __restrict__ Wout,
    u16* __restrict__ plane0, u16* __restrict__ wh,
    const int* __restrict__ d0, const int* __restrict__ d1,
    const int* __restrict__ d2, int* __restrict__ ghist,
    int NA, int NB, int E, int total, int K) {
    __shared__ int h[1024];
    int nA4 = NA * 16, nB4 = NB * 16;
    int bA = (nA4 + 255) / 256, bB = (nB4 + 255) / 256;
    int bi = blockIdx.x;
    int tid = threadIdx.x;
    if (bi < bA + bB) {
        const float* in = (bi < bA) ? xA : xB;
        u16* out = (bi < bA) ? plane0 : plane0 + (size_t)NA * 64;
        int i = (bi < bA ? bi : bi - bA) * 256 + tid;
        int n4 = (bi < bA) ? nA4 : nB4;
        if (i >= n4) return;
        float4 v = ((const float4*)in)[i];
        u16 o[4];
        o[0] = (u16)f2bs(v.x); o[1] = (u16)f2bs(v.y);
        o[2] = (u16)f2bs(v.z); o[3] = (u16)f2bs(v.w);
        *(uint2*)(out + (size_t)i * 4) = *(uint2*)o;
        return;
    }
    if (bi < bA + bB + 11) {
        int mat = bi - bA - bB;      // 0..10
        u16* dstp = wh + (size_t)mat * 4096;
        for (int i = tid; i < 4096; i += 256) {
            int k = i >> 6, n = i & 63;
            float v;
            if (mat < 6) v = Wn[(size_t)mat * 4096 + i];
            else if (mat < 8) v = Wr[(size_t)((mat - 6) * 3 + 0) * 4096 + i];
            else if (mat < 10) v = Wr[(size_t)((mat - 8) * 3 + 1) * 4096 + i]
                                 + Wr[(size_t)((mat - 8) * 3 + 2) * 4096 + i];
            else v = Wout[i];
            dstp[n * 64 + k] = (u16)f2bs(v);
        }
        return;
    }
    // ---- bucket_count portion (512 blocks, grid-stride) ----
    int cb = bi - (bA + bB + 11);
    for (int i = tid; i < 1024; i += 256) h[i] = 0;
    __syncthreads();
    for (int i = cb * 256 + tid; i < total; i += 512 * 256) {
        int g;
        if (i < E) g = d0[i];
        else if (i < 2 * E) g = NB + d1[i - E];
        else g = NB + NA + d2[i - 2 * E];
        atomicAdd(&h[g >> BSHIFT], 1);
    }
    __syncthreads();
    for (int i = tid; i < K; i += 256)
        if (h[i]) atomicAdd(&ghist[i], h[i]);
}

__global__ __launch_bounds__(256) void bucket_scan(const int* __restrict__ ghist,
                                                   int* __restrict__ bbase,
                                                   int* __restrict__ gcursor,
                                                   int K, int total) {
    __shared__ int ssum[256];
    int tid = threadIdx.x;
    int v[4]; int s = 0;
#pragma unroll
    for (int j = 0; j < 4; j++) {
        int i = tid * 4 + j;
        v[j] = s;
        s += (i < K) ? ghist[i] : 0;
    }
    ssum[tid] = s; __syncthreads();
    for (int off = 1; off < 256; off <<= 1) {
        int t = (tid >= off) ? ssum[tid - off] : 0; __syncthreads();
        ssum[tid] += t; __syncthreads();
    }
    int exc = tid ? ssum[tid - 1] : 0;
#pragma unroll
    for (int j = 0; j < 4; j++) {
        int i = tid * 4 + j;
        if (i < K) { bbase[i] = exc + v[j]; gcursor[i] = exc + v[j]; }
    }
    if (tid == 255) bbase[K] = total;
}

// pairs entry: packed = ((g & 1023) << 17) | src   (src < 2^17, bucket = g >> 10)
__global__ __launch_bounds__(256) void partition_kernel(
    const int* __restrict__ s0, const int* __restrict__ d0,
    const int* __restrict__ s1, const int* __restrict__ d1,
    const int* __restrict__ s2, const int* __restrict__ d2,
    int* __restrict__ gcursor, int* __restrict__ pairs,
    int NB, int NA, int E, int total) {
    __shared__ int hist[1024];
    __shared__ int gbase[1024];
    __shared__ int ssum[256];
    __shared__ int2 buf[TILE];   // {packed, bkt}
    int tid = threadIdx.x;
    for (int tile = blockIdx.x * TILE; tile < total; tile += gridDim.x * TILE) {
        for (int i = tid; i < 1024; i += 256) hist[i] = 0;
        __syncthreads();
        int cnt = min(TILE, total - tile);
        int mybkt[32], mypk[32], myrank[32];
#pragma unroll
        for (int j = 0; j < 32; j++) {
            int idx = tile + j * 256 + tid;
            int g = -1, s = 0;
            if (idx < total) {
                if (idx < E) { s = s0[idx]; g = d0[idx]; }
                else if (idx < 2 * E) { s = s1[idx - E]; g = NB + d1[idx - E]; }
                else { s = s2[idx - 2 * E]; g = NB + NA + d2[idx - 2 * E]; }
            }
            if (g >= 0) {
                mybkt[j] = g >> BSHIFT;
                mypk[j] = ((g & ((1 << BSHIFT) - 1)) << 17) | s;
                myrank[j] = atomicAdd(&hist[mybkt[j]], 1);
            } else mybkt[j] = -1;
        }
        __syncthreads();
        int l[4]; int base4 = tid * 4; int ts = 0;
#pragma unroll
        for (int j = 0; j < 4; j++) { l[j] = hist[base4 + j]; ts += l[j]; }
        ssum[tid] = ts; __syncthreads();
        for (int off = 1; off < 256; off <<= 1) {
            int t = (tid >= off) ? ssum[tid - off] : 0; __syncthreads();
            ssum[tid] += t; __syncthreads();
        }
        int exc = tid ? ssum[tid - 1] : 0;
#pragma unroll
        for (int j = 0; j < 4; j++) {
            hist[base4 + j] = exc;
            if (l[j]) gbase[base4 + j] = atomicAdd(&gcursor[base4 + j], l[j]);
            exc += l[j];
        }
        __syncthreads();
#pragma unroll
        for (int j = 0; j < 32; j++) {
            if (mybkt[j] >= 0)
                buf[hist[mybkt[j]] + myrank[j]] = make_int2(mypk[j], mybkt[j]);
        }
        __syncthreads();
        for (int i = tid; i < cnt; i += 256) {
            int2 p = buf[i];
            pairs[gbase[p.y] + (i - hist[p.y])] = p.x;
        }
        __syncthreads();
    }
}

__global__ __launch_bounds__(256) void bucket_fill(const int* __restrict__ pairs,
                                                   const int* __restrict__ bbase,
                                                   int* __restrict__ off,
                                                   int* __restrict__ colidx,
                                                   int M, int K) {
    int b = blockIdx.x;
    int gb = b << BSHIFT;
    __shared__ int cnt[1024], cur[1024], ssum[256];
    int tid = threadIdx.x;
    int p0 = bbase[b], p1 = bbase[b + 1];
    for (int i = tid; i < 1024; i += 256) cnt[i] = 0;
    __syncthreads();
    for (int e = p0 + tid; e < p1; e += 256)
        atomicAdd(&cnt[(unsigned)pairs[e] >> 17], 1);
    __syncthreads();
    int l[4], ts = 0;
#pragma unroll
    for (int j = 0; j < 4; j++) { l[j] = cnt[tid * 4 + j]; ts += l[j]; }
    ssum[tid] = ts; __syncthreads();
    for (int o = 1; o < 256; o <<= 1) {
        int t = (tid >= o) ? ssum[tid - o] : 0; __syncthreads();
        ssum[tid] += t; __syncthreads();
    }
    int exc = tid ? ssum[tid - 1] : 0;
#pragma unroll
    for (int j = 0; j < 4; j++) {
        cur[tid * 4 + j] = exc;
        int g = gb + tid * 4 + j;
        if (g < M) off[g] = p0 + exc;
        exc += l[j];
    }
    if (b == K - 1 && tid == 0) off[M] = p1;
    __syncthreads();
    for (int e = p0 + tid; e < p1; e += 256) {
        int p = pairs[e];
        int pos = atomicAdd(&cur[(unsigned)p >> 17], 1);
        colidx[p0 + pos] = p & 0x1FFFF;
    }
}

// ---------------- gather-mean: quarter-wave, 32-bit offsets ----------------
__global__ __launch_bounds__(256) void gather_all(const u16* __restrict__ plane,
                                                  const int* __restrict__ colidx,
                                                  const int* __restrict__ off,
                                                  u16* __restrict__ meanB,
                                                  u16* __restrict__ meanA1,
                                                  u16* __restrict__ meanA2,
                                                  int NB, int NA) {
    int wid = (blockIdx.x * 256 + threadIdx.x) >> 6;
    int lane = threadIdx.x & 63;
    int M = NB + 2 * NA;
    if (wid >= M) return;
    const char* tab;
    u16* outp;
    int orow;
    if (wid < NB) { tab = (const char*)plane; outp = meanB; orow = wid; }
    else if (wid < NB + NA) { tab = (const char*)(plane + (size_t)NA * 64); outp = meanA1; orow = wid - NB; }
    else { tab = (const char*)plane; outp = meanA2; orow = wid - NB - NA; }

    int s0 = off[wid], s1 = off[wid + 1];
    int qh = lane >> 4, fl = lane & 15;
    unsigned fo = (unsigned)(fl << 3);
    f32x4 a0 = {0.f, 0.f, 0.f, 0.f}, a1 = {0.f, 0.f, 0.f, 0.f};
    int e = s0 + qh;
    for (; e + 4 < s1; e += 8) {
        int c0 = *(const int*)((const char*)colidx + ((unsigned)e << 2));
        int c1 = *(const int*)((const char*)colidx + ((unsigned)(e + 4) << 2));
        uint2 u0 = *(const uint2*)(tab + (((unsigned)c0 << 7) | fo));
        uint2 u1 = *(const uint2*)(tab + (((unsigned)c1 << 7) | fo));
        a0[0] += uif(u0.x << 16); a0[1] += uif(u0.x & 0xFFFF0000u);
        a0[2] += uif(u0.y << 16); a0[3] += uif(u0.y & 0xFFFF0000u);
        a1[0] += uif(u1.x << 16); a1[1] += uif(u1.x & 0xFFFF0000u);
        a1[2] += uif(u1.y << 16); a1[3] += uif(u1.y & 0xFFFF0000u);
    }
    for (; e < s1; e += 4) {
        int c = *(const int*)((const char*)colidx + ((unsigned)e << 2));
        uint2 u = *(const uint2*)(tab + (((unsigned)c << 7) | fo));
        a0[0] += uif(u.x << 16); a0[1] += uif(u.x & 0xFFFF0000u);
        a0[2] += uif(u.y << 16); a0[3] += uif(u.y & 0xFFFF0000u);
    }
#pragma unroll
    for (int i = 0; i < 4; i++) {
        a0[i] += a1[i];
        a0[i] += __shfl_xor(a0[i], 16);
        a0[i] += __shfl_xor(a0[i], 32);
    }
    if (qh == 0) {
        float inv = 1.0f / fmaxf((float)(s1 - s0), 1.0f);
        u16 o[4];
#pragma unroll
        for (int i = 0; i < 4; i++) o[i] = (u16)f2bs(a0[i] * inv);
        *(uint2*)(outp + (size_t)orow * 64 + fl * 4) = *(uint2*)o;
    }
}

// ---------------- fused linear body (bf16 in, MFMA, bf16 or f32 out) ----------------
// A[m=lane&15][k=(lane>>4)*8+j], B[k][n=lane&15] (pre-transposed),
// C/D row=(lane>>4)*4+reg, col=lane&15.
template <int NM, int RELU, int OUTF32>
__device__ __forceinline__ void lin_body(
    const u16* __restrict__ m0, const u16* __restrict__ m1,
    const u16* __restrict__ x,
    const u16* __restrict__ Wm0t, const u16* __restrict__ Wm1t,
    const u16* __restrict__ Wxt,
    const float* __restrict__ bias0, const float* __restrict__ bias1,
    void* __restrict__ outv, int nrows, int blk) {
    const int lane = threadIdx.x & 63;
    const int wave = threadIdx.x >> 6;
    const int row0 = blk * 64 + wave * 16;
    if (row0 >= nrows) return;
    const int r = lane & 15;
    const int q = lane >> 4;

    short8 wm0f[2][4], wm1f[2][4], wxf[2][4];
#pragma unroll
    for (int ks = 0; ks < 2; ks++) {
#pragma unroll
        for (int t = 0; t < 4; t++) {
            size_t widx = (size_t)(t * 16 + r) * 64 + ks * 32 + q * 8;
            if (NM >= 1) wm0f[ks][t] = *(const short8*)(Wm0t + widx);
            if (NM >= 2) wm1f[ks][t] = *(const short8*)(Wm1t + widx);
            wxf[ks][t] = *(const short8*)(Wxt + widx);
        }
    }

    f32x4 acc[4];
#pragma unroll
    for (int t = 0; t < 4; t++) {
        float bv = bias0[t * 16 + r];
        if (bias1) bv += bias1[t * 16 + r];
        acc[t][0] = bv; acc[t][1] = bv; acc[t][2] = bv; acc[t][3] = bv;
    }

    const int arow = row0 + r;
    const bool avalid = arow < nrows;
    short8 zf;
#pragma unroll
    for (int j = 0; j < 8; j++) zf[j] = 0;

    if (NM >= 1) {
#pragma unroll
        for (int ks = 0; ks < 2; ks++) {
            short8 af = avalid ? *(const short8*)(m0 + (size_t)arow * 64 + ks * 32 + q * 8) : zf;
#pragma unroll
            for (int t = 0; t < 4; t++)
                acc[t] = __builtin_amdgcn_mfma_f32_16x16x32_bf16(af, wm0f[ks][t], acc[t], 0, 0, 0);
        }
    }
    if (NM >= 2) {
#pragma unroll
        for (int ks = 0; ks < 2; ks++) {
            short8 af = avalid ? *(const short8*)(m1 + (size_t)arow * 64 + ks * 32 + q * 8) : zf;
#pragma unroll
            for (int t = 0; t < 4; t++)
                acc[t] = __builtin_amdgcn_mfma_f32_16x16x32_bf16(af, wm1f[ks][t], acc[t], 0, 0, 0);
        }
    }
#pragma unroll
    for (int ks = 0; ks < 2; ks++) {
        short8 xf = avalid ? *(const short8*)(x + (size_t)arow * 64 + ks * 32 + q * 8) : zf;
#pragma unroll
        for (int t = 0; t < 4; t++)
            acc[t] = __builtin_amdgcn_mfma_f32_16x16x32_bf16(xf, wxf[ks][t], acc[t], 0, 0, 0);
    }

#pragma unroll
    for (int t = 0; t < 4; t++) {
#pragma unroll
        for (int rr = 0; rr < 4; rr++) {
            int row = row0 + q * 4 + rr;
            if (row < nrows) {
                float v = acc[t][rr];
                if (RELU) v = fmaxf(v, 0.0f);
                if (OUTF32) ((float*)outv)[(size_t)row * 64 + t * 16 + r] = v;
                else ((u16*)outv)[(size_t)row * 64 + t * 16 + r] = (u16)f2bs(v);
            }
        }
    }
}

// one layer: B-phase blocks [0,blocksB), A-phase blocks [blocksB, ...)
__global__ __launch_bounds__(256) void layer_kernel(
    const u16* __restrict__ plane_in, u16* __restrict__ plane_out,
    const u16* __restrict__ meanB, const u16* __restrict__ meanA1,
    const u16* __restrict__ meanA2, const u16* __restrict__ wh,
    const float* __restrict__ bvec, int l, int NA, int NB, int blocksB) {
    if ((int)blockIdx.x < blocksB) {
        // new_B = mean(A->B)@Wn[l,0] + x_B@Wr[l,0] + b[l,0]
        lin_body<1, 0, 0>(meanB, nullptr, plane_in + (size_t)NA * 64,
                          wh + (size_t)(l * 3 + 0) * 4096, nullptr,
                          wh + (size_t)(6 + l) * 4096,
                          bvec + (size_t)(l * 3 + 0) * 64, nullptr,
                          plane_out + (size_t)NA * 64, NB, blockIdx.x);
    } else {
        // new_A = mean(B->A)@Wn[l,1] + mean(A->A)@Wn[l,2] + x_A@(Wr[l,1]+Wr[l,2]) + b[l,1]+b[l,2]
        lin_body<2, 0, 0>(meanA1, meanA2, plane_in,
                          wh + (size_t)(l * 3 + 1) * 4096, wh + (size_t)(l * 3 + 2) * 4096,
                          wh + (size_t)(8 + l) * 4096,
                          bvec + (size_t)(l * 3 + 1) * 64, bvec + (size_t)(l * 3 + 2) * 64,
                          plane_out, NA, blockIdx.x - blocksB);
    }
}

// head over NA+NB contiguous rows
__global__ __launch_bounds__(256) void head_kernel(
    const u16* __restrict__ plane_in, const u16* __restrict__ wh,
    const float* __restrict__ b_out, float* __restrict__ out, int nrows) {
    lin_body<0, 1, 1>(nullptr, nullptr, plane_in,
                      nullptr, nullptr, wh + (size_t)10 * 4096,
                      b_out, nullptr, out, nrows, blockIdx.x);
}

// ---------------- launch ----------------
extern "C" void kernel_launch(void* const* d_in, const int* in_sizes, int n_in,
                              void* d_out, int out_size, void* d_ws, size_t ws_size,
                              hipStream_t stream) {
    const float* xA_in = (const float*)d_in[0];
    const float* xB_in = (const float*)d_in[1];
    const float* Wn = (const float*)d_in[2];
    const float* Wr = (const float*)d_in[3];
    const float* b = (const float*)d_in[4];
    const float* W_out = (const float*)d_in[5];
    const float* b_out = (const float*)d_in[6];
    const int* src0 = (const int*)d_in[7];
    const int* dst0 = (const int*)d_in[8];
    const int* src1 = (const int*)d_in[9];
    const int* dst1 = (const int*)d_in[10];
    const int* src2 = (const int*)d_in[11];
    const int* dst2 = (const int*)d_in[12];

    const int NA = in_sizes[0] / 64;
    const int NB = in_sizes[1] / 64;
    const int E = in_sizes[7];
    const int M = NB + NA + NA;
    const int total = 3 * E;
    const int K = (M + (1 << BSHIFT) - 1) >> BSHIFT;

    // ---- workspace ----
    const size_t PL = (size_t)(NA + NB) * 64;
    u16* plane[2];
    plane[0] = (u16*)d_ws;
    plane[1] = plane[0] + PL;
    u16* wh     = plane[1] + PL;                 // 11*4096
    u16* meanB  = wh + 11 * 4096;
    u16* meanA1 = meanB + (size_t)NB * 64;
    u16* meanA2 = meanA1 + (size_t)NA * 64;
    int* ghist  = (int*)(meanA2 + (size_t)NA * 64);
    int* bbase  = ghist + 1024;
    int* gcursor= bbase + 1025;
    int* off    = gcursor + 1024;
    int* colidx = off + (M + 1);
    int* pairs  = (int*)meanB;   // aliases means region (dead until gathers run)

    // ---- prep + count ----
    int bA = (NA * 16 + 255) / 256, bB = (NB * 16 + 255) / 256;
    hipMemsetAsync(ghist, 0, 1024 * 4, stream);
    prep_count<<<bA + bB + 11 + 512, 256, 0, stream>>>(
        xA_in, xB_in, Wn, Wr, W_out, plane[0], wh,
        dst0, dst1, dst2, ghist, NA, NB, E, total, K);

    // ---- CSR build ----
    bucket_scan<<<1, 256, 0, stream>>>(ghist, bbase, gcursor, K, total);
    int ntiles = (total + TILE - 1) / TILE;
    partition_kernel<<<ntiles, 256, 0, stream>>>(src0, dst0, src1, dst1, src2, dst2,
                                                 gcursor, pairs, NB, NA, E, total);
    bucket_fill<<<K, 256, 0, stream>>>(pairs, bbase, off, colidx, M, K);

    // ---- layers ----
    const int blocksB = (NB + 63) / 64;
    const int blocksA = (NA + 63) / 64;
    int p = 0;
    for (int l = 0; l < 2; l++) {
        gather_all<<<(M + 3) / 4, 256, 0, stream>>>(plane[p], colidx, off,
                                                    meanB, meanA1, meanA2, NB, NA);
        layer_kernel<<<blocksB + blocksA, 256, 0, stream>>>(
            plane[p], plane[1 - p], meanB, meanA1, meanA2, wh, b, l, NA, NB, blocksB);
        p = 1 - p;
    }

    // ---- head ----
    head_kernel<<<(NA + NB + 63) / 64, 256, 0, stream>>>(
        plane[p], wh, b_out, (float*)d_out, NA + NB);
}